// Round 9
// baseline (697.997 us; speedup 1.0000x reference)
//
#include <hip/hip_runtime.h>
#include <hip/hip_bf16.h>

// Problem constants (from reference)
#define S_LEN   2048
#define BATCH   4
#define IN_DIM  64
#define H_DIM   1024
#define DFF_DIM 1024
#define OUT_DIM 64
#define NLAYER  3
#define NHEADS  4
#define DHEAD   256     // H / NHEAD
#define WIN     4       // banded window: j in [i-4, i]
#define ROWS    (S_LEN*BATCH)  // 8192 flattened (s,b) rows, row = s*B + b
#define QKV_LD  (3*H_DIM)      // 3072

// Established facts (rounds 0-19):
//  - r16/r18 = 682-696 us (run noise ~±10): QKV gemm_bt (59.5 us, 858 TF,
//    FETCH 51 MB), Wo/W1/W2 gemm8 (~31 us), enc/dec gemm_bt.
//  - CLOSED: deep pipelines (r11/r12/r14/r15 all ~700 TF), XCD remaps
//    (r17: lin&7 map -> FETCH 51->73 MB regression; supertile is best).
//  - r19 (this): 32x32x16 MFMA in gemm_bt only. ubench: 2382 TF vs 2075
//    (16x16x32) per-cycle +15%, and HALF the MFMA instruction count (16 vs
//    32 per K-tile/wave) -> less issue pressure. Same ds_read count/pattern
//    (chunk = ks*2+(lane>>5), XOR row&7 swizzle unchanged, conflict-free).
//    A/B layout: row/col = lane&31, k = (lane>>5)*8+j (analog of verified
//    16x16x32 mapping). C/D: col=lane&31, row=(reg&3)+8*(reg>>2)+4*(lane>>5)
//    [m74/m101 HW-verified]. acc f32x16[2][2] = 64 VGPR (unchanged).
//    gemm8 untouched (contained surgery). Predict QKV 59.5 -> ~56 us.
//    If null: MFMA pipe is off the critical path; declare ceiling next.

typedef __bf16 bf16x8 __attribute__((ext_vector_type(8)));
typedef float  f32x4  __attribute__((ext_vector_type(4)));
typedef float  f32x16 __attribute__((ext_vector_type(16)));

__device__ __forceinline__ float bfbits2f(unsigned int u) {
  union { unsigned int i; float f; } c; c.i = u << 16; return c.f;
}
__device__ __forceinline__ unsigned short f2bfbits(float f) {
  __hip_bfloat16 h = __float2bfloat16(f);
  return __builtin_bit_cast(unsigned short, h);
}

// async global->LDS, 16B per lane. LDS dest = wave-uniform base + lane*16.
__device__ __forceinline__ void g2l16(const void* g, void* l) {
  __builtin_amdgcn_global_load_lds((__attribute__((address_space(1))) void*)g,
                                   (__attribute__((address_space(3))) void*)l,
                                   16, 0, 0);
}

// ---------------------------------------------------------------------------
// Merged fp32->bf16 ingest: all 7 weight/src segments in ONE dispatch.
// ---------------------------------------------------------------------------
struct CvtSeg { const float* src; __hip_bfloat16* dst; int n4; };  // n4 = n/4

__global__ __launch_bounds__(256)
void cvt_all_k(CvtSeg s0, CvtSeg s1, CvtSeg s2, CvtSeg s3,
               CvtSeg s4, CvtSeg s5, CvtSeg s6)
{
  int i = blockIdx.x * 256 + threadIdx.x;   // index in unit of 4 elems
  CvtSeg seg;
  if      (i < s0.n4) { seg = s0; }
  else if ((i -= s0.n4) < s1.n4) { seg = s1; }
  else if ((i -= s1.n4) < s2.n4) { seg = s2; }
  else if ((i -= s2.n4) < s3.n4) { seg = s3; }
  else if ((i -= s3.n4) < s4.n4) { seg = s4; }
  else if ((i -= s4.n4) < s5.n4) { seg = s5; }
  else if ((i -= s5.n4) < s6.n4) { seg = s6; }
  else return;
  float4 v = *(const float4*)(seg.src + (size_t)i * 4);
  uint2 o;
  o.x = (unsigned)f2bfbits(v.x) | ((unsigned)f2bfbits(v.y) << 16);
  o.y = (unsigned)f2bfbits(v.z) | ((unsigned)f2bfbits(v.w) << 16);
  *(uint2*)(seg.dst + (size_t)i * 4) = o;
}

// ---------------------------------------------------------------------------
// gemm_bt: 128x128 tile, BK=64, 256 thr, 2 blk/CU — encoder, QKV, decoder.
// r19: inner compute uses v_mfma_f32_32x32x16_bf16 (2x2 blocks x 4 k-steps
// = 16 MFMA/K-tile/wave, half the instruction count of 16x16x32).
// ---------------------------------------------------------------------------
template<int RELU, int OUTF32, int ADDRES>
__global__ __launch_bounds__(256, 2)
void gemm_bt(const __hip_bfloat16* __restrict__ A, int lda,
             const __hip_bfloat16* __restrict__ B,
             const float* __restrict__ bias,
             void* __restrict__ Cp, int ldc,
             const __hip_bfloat16* __restrict__ R, int ldr,
             int M, int N, int K)
{
  __shared__ __align__(16) __hip_bfloat16 As[128 * 64];
  __shared__ __align__(16) __hip_bfloat16 Bs[128 * 64];

  const int tid  = threadIdx.x;
  const int lane = tid & 63;
  const int wave = tid >> 6;
  const int l32  = lane & 31;     // row/col within 32-block
  const int hi   = lane >> 5;     // k-half selector (0/1)

  const int gx  = gridDim.x;
  const int lin = blockIdx.y * gx + blockIdx.x;
  const int gsz = 4 * gx;
  const int mt  = (lin / gsz) * 4 + (lin & 3);
  const int nt  = (lin % gsz) >> 2;
  const int m0 = mt * 128;
  const int n0 = nt * 128;

  const int wr = (wave >> 1) * 64;   // wave's 64x64 sub-tile
  const int wc = (wave & 1) * 64;

  int arow[4], acol[4], brow[4];
#pragma unroll
  for (int s = 0; s < 4; s++) {
    const int p = tid + (s << 8);
    arow[s] = p >> 3;
    acol[s] = ((p & 7) ^ ((p >> 3) & 7)) * 8;
    brow[s] = min(n0 + arow[s], N - 1);   // clamp for N edge
  }

  f32x16 acc[2][2] = {};
  const int nk = K >> 6;

  for (int t = 0; t < nk; ++t) {
    const int k0 = t << 6;
#pragma unroll
    for (int s = 0; s < 4; s++) {
      const int lo = (wave * 64 + (s << 8)) * 8;   // chunk*8 elems
      g2l16(A + (size_t)(m0 + arow[s]) * lda + k0 + acol[s], &As[lo]);
      g2l16(B + (size_t)brow[s] * K + k0 + acol[s], &Bs[lo]);
    }
    __syncthreads();

    // 32x32x16 path: k-step ks = kh*2+s covers k = ks*16 + hi*8 + j;
    // logical chunk c8 = ks*2 + hi; physical = c8 ^ (row&7).
#pragma unroll
    for (int kh = 0; kh < 2; kh++) {
      bf16x8 af[2][2], bfr[2][2];   // [block][ks-sub]
#pragma unroll
      for (int bi = 0; bi < 2; bi++) {
        const int row = wr + bi * 32 + l32;
        const int sw  = row & 7;
#pragma unroll
        for (int s = 0; s < 2; s++) {
          const int c8 = ((kh * 2 + s) * 2 + hi) ^ sw;
          af[bi][s] = *(const bf16x8*)&As[row * 64 + c8 * 8];
        }
      }
#pragma unroll
      for (int bj = 0; bj < 2; bj++) {
        const int row = wc + bj * 32 + l32;
        const int sw  = row & 7;
#pragma unroll
        for (int s = 0; s < 2; s++) {
          const int c8 = ((kh * 2 + s) * 2 + hi) ^ sw;
          bfr[bj][s] = *(const bf16x8*)&Bs[row * 64 + c8 * 8];
        }
      }
#pragma unroll
      for (int s = 0; s < 2; s++)
#pragma unroll
        for (int bi = 0; bi < 2; bi++)
#pragma unroll
          for (int bj = 0; bj < 2; bj++)
            acc[bi][bj] = __builtin_amdgcn_mfma_f32_32x32x16_bf16(
                af[bi][s], bfr[bj][s], acc[bi][bj], 0, 0, 0);
    }
    __syncthreads();
  }

  // epilogue: C/D layout col = lane&31, row = (reg&3) + 8*(reg>>2) + 4*hi
#pragma unroll
  for (int bj = 0; bj < 2; bj++) {
    const int col = n0 + wc + bj * 32 + l32;
    if (col < N) {
      const float bv = bias[col];
#pragma unroll
      for (int bi = 0; bi < 2; bi++) {
        const int rbase = m0 + wr + bi * 32 + 4 * hi;
#pragma unroll
        for (int r = 0; r < 16; r++) {
          const int row = rbase + (r & 3) + 8 * (r >> 2);
          float v = acc[bi][bj][r] + bv;
          if (RELU) v = fmaxf(v, 0.f);
          if (ADDRES) v += __bfloat162float(R[(size_t)row * ldr + col]);
          if (OUTF32) ((float*)Cp)[(size_t)row * ldc + col] = v;
          else ((__hip_bfloat16*)Cp)[(size_t)row * ldc + col] = __float2bfloat16(v);
        }
      }
    }
  }
}

// ---------------------------------------------------------------------------
// gemm8_bt: 128(M)x256(N), BK=64, 512 thr (8 waves 2Mx4N, wave owns 64x64),
// 8-phase window over 2 K-tiles, 1 half-slot stage/phase, vmcnt(4) at ph4/8.
// Measured-best for Wo/W1/W2 (N=1024 -> 256 blocks, exact 1-round packing).
// UNCHANGED from r16/r18 (16x16x32 MFMA).
// ---------------------------------------------------------------------------
#define ST_A(BUF, H, KO)                                                      \
  g2l16(Ab + (size_t)((H) * 64 + sarow) * lda + (KO) + sacol,                 \
        &lds[BUF][(H) << 12] + (tid << 3))
#define ST_B(BUF, H, KO)                                                      \
  do {                                                                        \
    g2l16(Bb + (size_t)((H) * 128 + sbrow) * K + (KO) + sbcol,                \
          &lds[BUF][8192 + ((H) << 13)] + (tid << 3));                        \
    g2l16(Bb + (size_t)((H) * 128 + sbrow + 64) * K + (KO) + sbcol,           \
          &lds[BUF][8192 + ((H) << 13)] + ((tid + 512) << 3));                \
  } while (0)

#define RD_AF(ASL, FRB)                                                       \
  do {                                                                        \
    _Pragma("unroll") for (int j_ = 0; j_ < 2; j_++) {                        \
      const int r_ = ((FRB) + j_) * 16 + l16;                                 \
      const int x_ = r_ & 7;                                                  \
      af[j_][0] = *(const bf16x8*)&(ASL)[r_ * 64 + ((quad ^ x_) << 3)];       \
      af[j_][1] = *(const bf16x8*)&(ASL)[r_ * 64 + (((4 + quad) ^ x_) << 3)]; \
    }                                                                         \
  } while (0)
#define RD_BQ(BSL, FCB)                                                       \
  do {                                                                        \
    _Pragma("unroll") for (int j_ = 0; j_ < 2; j_++) {                        \
      const int r_ = brow_base + ((FCB) + j_) * 16 + l16;                     \
      const int x_ = r_ & 7;                                                  \
      bq[(FCB) + j_][0] = *(const bf16x8*)&(BSL)[r_ * 64 + ((quad ^ x_) << 3)]; \
      bq[(FCB) + j_][1] = *(const bf16x8*)&(BSL)[r_ * 64 + (((4 + quad) ^ x_) << 3)]; \
    }                                                                         \
  } while (0)
#define MM(FRB, FCB)                                                          \
  do {                                                                        \
    _Pragma("unroll") for (int ks_ = 0; ks_ < 2; ks_++)                       \
      _Pragma("unroll") for (int i_ = 0; i_ < 2; i_++)                        \
        _Pragma("unroll") for (int j_ = 0; j_ < 2; j_++)                      \
          acc[(FRB) + i_][(FCB) + j_] =                                       \
              __builtin_amdgcn_mfma_f32_16x16x32_bf16(                        \
                  af[i_][ks_], bq[(FCB) + j_][ks_],                           \
                  acc[(FRB) + i_][(FCB) + j_], 0, 0, 0);                      \
  } while (0)

#define PH8(READS, STAGE, WAIT, MFMA)                                         \
  do {                                                                        \
    READS; STAGE; WAIT;                                                       \
    __builtin_amdgcn_s_barrier();                                             \
    asm volatile("s_waitcnt lgkmcnt(0)" ::: "memory");                        \
    __builtin_amdgcn_sched_barrier(0);                                        \
    __builtin_amdgcn_s_setprio(1);                                            \
    MFMA;                                                                     \
    __builtin_amdgcn_s_setprio(0);                                            \
    __builtin_amdgcn_s_barrier();                                             \
  } while (0)

#define W4CNT                                                                 \
  do {                                                                        \
    if (pf) { asm volatile("s_waitcnt vmcnt(4)" ::: "memory"); }              \
    else    { asm volatile("s_waitcnt vmcnt(0)" ::: "memory"); }              \
  } while (0)

template<int RELU, int ADDRES>
__global__ __launch_bounds__(512, 1)
void gemm8_bt(const __hip_bfloat16* __restrict__ A, int lda,
              const __hip_bfloat16* __restrict__ B,
              const float* __restrict__ bias,
              __hip_bfloat16* __restrict__ C, int ldc,
              const __hip_bfloat16* __restrict__ Rr, int ldr,
              int K)
{
  __shared__ __align__(16) __hip_bfloat16 lds[2][24576];  // 96 KiB

  const int tid  = threadIdx.x;
  const int lane = tid & 63;
  const int wave = tid >> 6;
  const int quad = lane >> 4;
  const int l16  = lane & 15;
  const int wm   = wave >> 2;        // 0..1 (M half)
  const int wn   = wave & 3;         // 0..3 (N quarter)
  const int bh   = wn >> 1;          // wave's B-half
  const int brow_base = (wn & 1) * 64;

  const int gx  = gridDim.x;
  const int lin = blockIdx.y * gx + blockIdx.x;
  const int gsz = 4 * gx;
  const int mt  = (lin / gsz) * 4 + (lin & 3);
  const int nt  = (lin % gsz) >> 2;
  const int m0 = mt * 128;
  const int n0 = nt * 256;

  const __hip_bfloat16* Ab = A + (size_t)m0 * lda;
  const __hip_bfloat16* Bb = B + (size_t)n0 * K;

  const int sarow = tid >> 3;                         // A: rows 0..63
  const int sacol = ((tid & 7) ^ (sarow & 7)) << 3;
  const int sbrow = sarow;
  const int sbcol = sacol;

  const __hip_bfloat16* As0 = &lds[0][wm << 12];
  const __hip_bfloat16* As1 = &lds[1][wm << 12];
  const __hip_bfloat16* Bs0 = &lds[0][8192 + (bh << 13)];
  const __hip_bfloat16* Bs1 = &lds[1][8192 + (bh << 13)];

  f32x4 acc[4][4] = {};
  bf16x8 af[2][2], bq[4][2];

  const int NI = K >> 7;   // iterations of 2 K-tiles

  ST_A(0, 0, 0); ST_A(0, 1, 0);
  ST_B(0, 0, 0); ST_B(0, 1, 0);
  ST_B(1, 0, 64); ST_B(1, 1, 64);
  asm volatile("s_waitcnt vmcnt(4)" ::: "memory");   // buf0 landed
  __builtin_amdgcn_s_barrier();

  for (int i = 0; i < NI; ++i) {
    const int k1 = (i << 7) + 64;    // K-tile 2i+1
    const int k2 = k1 + 64;          // K-tile 2i+2
    const int k3 = k1 + 128;         // K-tile 2i+3
    const bool pf = (i + 1) < NI;

    PH8(RD_AF(As0, 0); RD_BQ(Bs0, 0),  ST_A(1, 0, k1),              , MM(0, 0));
    PH8(RD_BQ(Bs0, 2),                 ST_A(1, 1, k1),              , MM(0, 2));
    PH8(RD_AF(As0, 2),                 if (pf) ST_B(0, 0, k2),      , MM(2, 0));
    PH8(                             , if (pf) ST_B(0, 1, k2), W4CNT, MM(2, 2));
    PH8(RD_AF(As1, 0); RD_BQ(Bs1, 0),  if (pf) ST_A(0, 0, k2),      , MM(0, 0));
    PH8(RD_BQ(Bs1, 2),                 if (pf) ST_A(0, 1, k2),      , MM(0, 2));
    PH8(RD_AF(As1, 2),                 if (pf) ST_B(1, 0, k3),      , MM(2, 0));
    PH8(                             , if (pf) ST_B(1, 1, k3), W4CNT, MM(2, 2));
  }

#pragma unroll
  for (int jn = 0; jn < 4; jn++) {
    const int col = n0 + wn * 64 + jn * 16 + l16;
    const float bv = bias[col];
#pragma unroll
    for (int im = 0; im < 4; im++) {
      const int row0 = m0 + wm * 64 + im * 16 + quad * 4;
      const f32x4 a = acc[im][jn];
#pragma unroll
      for (int rr = 0; rr < 4; rr++) {
        float v = a[rr] + bv;
        if (RELU) v = fmaxf(v, 0.f);
        if (ADDRES) v += __bfloat162float(Rr[(size_t)(row0 + rr) * ldr + col]);
        C[(size_t)(row0 + rr) * ldc + col] = __float2bfloat16(v);
      }
    }
  }
}

// ---------------------------------------------------------------------------
// Banded attention (one wave per (s,b,h)).
// ---------------------------------------------------------------------------
__global__ __launch_bounds__(256)
void attn_k(__hip_bfloat16* __restrict__ qkv)
{
  const int gw   = (blockIdx.x << 2) + (threadIdx.x >> 6);
  const int lane = threadIdx.x & 63;
  const int h = gw & (NHEADS - 1);
  const int b = (gw >> 2) & (BATCH - 1);
  const int s = gw >> 4;
  const size_t hoff = (size_t)h * DHEAD + (lane << 2);

  float q0, q1, q2, q3;
  {
    uint2 t = *(const uint2*)(qkv + (size_t)(s * BATCH + b) * QKV_LD + hoff);
    q0 = bfbits2f(t.x & 0xffff); q1 = bfbits2f(t.x >> 16);
    q2 = bfbits2f(t.y & 0xffff); q3 = bfbits2f(t.y >> 16);
  }

  float sc[WIN + 1];
#pragma unroll
  for (int jj = 0; jj <= WIN; jj++) {
    int j = s - WIN + jj;           // wave-uniform
    float v = -1e30f;
    if (j >= 0) {
      uint2 t = *(const uint2*)(qkv + (size_t)(j * BATCH + b) * QKV_LD + H_DIM + hoff);
      float p = q0 * bfbits2f(t.x & 0xffff) + q1 * bfbits2f(t.x >> 16)
              + q2 * bfbits2f(t.y & 0xffff) + q3 * bfbits2f(t.y >> 16);
#pragma unroll
      for (int o = 32; o; o >>= 1) p += __shfl_xor(p, o);
      v = p * 0.0625f;              // 1/sqrt(256)
    }
    sc[jj] = v;
  }

  float mx = sc[0];
#pragma unroll
  for (int jj = 1; jj <= WIN; jj++) mx = fmaxf(mx, sc[jj]);
  float p[WIN + 1], den = 0.f;
#pragma unroll
  for (int jj = 0; jj <= WIN; jj++) { p[jj] = __expf(sc[jj] - mx); den += p[jj]; }

  float a0 = 0.f, a1 = 0.f, a2 = 0.f, a3 = 0.f;
#pragma unroll
  for (int jj = 0; jj <= WIN; jj++) {
    int j = s - WIN + jj;
    if (j >= 0) {
      uint2 t = *(const uint2*)(qkv + (size_t)(j * BATCH + b) * QKV_LD + 2 * H_DIM + hoff);
      a0 += p[jj] * bfbits2f(t.x & 0xffff); a1 += p[jj] * bfbits2f(t.x >> 16);
      a2 += p[jj] * bfbits2f(t.y & 0xffff); a3 += p[jj] * bfbits2f(t.y >> 16);
    }
  }
  float rl = 1.f / den;
  uint2 o;
  o.x = (unsigned)f2bfbits(a0 * rl) | ((unsigned)f2bfbits(a1 * rl) << 16);
  o.y = (unsigned)f2bfbits(a2 * rl) | ((unsigned)f2bfbits(a3 * rl) << 16);
  *(uint2*)(qkv + (size_t)(s * BATCH + b) * QKV_LD + hoff) = o;  // ctx -> q slot
}

// ---------------------------------------------------------------------------
// LayerNorm, one wave per row (shuffle-only).
// ---------------------------------------------------------------------------
__global__ __launch_bounds__(256)
void ln_k(const __hip_bfloat16* __restrict__ y, int ys,
          const float* __restrict__ g, const float* __restrict__ be,
          __hip_bfloat16* __restrict__ xout)
{
  const int row  = blockIdx.x * 4 + (threadIdx.x >> 6);
  const int lane = threadIdx.x & 63;
  const int e0   = lane * 16;
  const __hip_bfloat16* yp = y + (size_t)row * ys + e0;

  uint2 v[4];
  *(uint4*)&v[0] = *(const uint4*)yp;
  *(uint4*)&v[2] = *(const uint4*)(yp + 8);
  float t[16];
#pragma unroll
  for (int k = 0; k < 4; k++) {
    t[k * 4 + 0] = bfbits2f(v[k].x & 0xffff);
    t[k * 4 + 1] = bfbits2f(v[k].x >> 16);
    t[k * 4 + 2] = bfbits2f(v[k].y & 0xffff);
    t[k * 4 + 3] = bfbits2f(v[k].y >> 16);
  }
  float s = 0.f, ss = 0.f;
#pragma unroll
  for (int k = 0; k < 16; k++) { s += t[k]; ss += t[k] * t[k]; }
#pragma unroll
  for (int o = 32; o; o >>= 1) { s += __shfl_xor(s, o); ss += __shfl_xor(ss, o); }

  const float inv  = 1.f / (float)H_DIM;
  const float mean = s * inv;
  const float var  = ss * inv - mean * mean;   // biased var (jnp.var default)
  const float rstd = rsqrtf(var + 1e-5f);

  float4 gv[4], bv[4];
#pragma unroll
  for (int k = 0; k < 4; k++) {
    gv[k] = *(const float4*)(g + e0 + k * 4);
    bv[k] = *(const float4*)(be + e0 + k * 4);
  }
  uint2 ob[4];
#pragma unroll
  for (int k = 0; k < 4; k++) {
    float o0 = (t[k*4+0] - mean) * rstd * gv[k].x + bv[k].x;
    float o1 = (t[k*4+1] - mean) * rstd * gv[k].y + bv[k].y;
    float o2 = (t[k*4+2] - mean) * rstd * gv[k].z + bv[k].z;
    float o3 = (t[k*4+3] - mean) * rstd * gv[k].w + bv[k].w;
    ob[k].x = (unsigned)f2bfbits(o0) | ((unsigned)f2bfbits(o1) << 16);
    ob[k].y = (unsigned)f2bfbits(o2) | ((unsigned)f2bfbits(o3) << 16);
  }
  __hip_bfloat16* xp = xout + (size_t)row * H_DIM + e0;
  *(uint4*)xp       = *(const uint4*)&ob[0];
  *(uint4*)(xp + 8) = *(const uint4*)&ob[2];
}

// ---------------------------------------------------------------------------
extern "C" void kernel_launch(void* const* d_in, const int* in_sizes, int n_in,
                              void* d_out, int out_size, void* d_ws, size_t ws_size,
                              hipStream_t stream) {
  const float* src   = (const float*)d_in[0];
  const float* Wenc  = (const float*)d_in[1];
  const float* benc  = (const float*)d_in[2];
  const float* Wqkv  = (const float*)d_in[3];
  const float* bqkv  = (const float*)d_in[4];
  const float* Wo    = (const float*)d_in[5];
  const float* bo    = (const float*)d_in[6];
  const float* W1    = (const float*)d_in[7];
  const float* b1    = (const float*)d_in[8];
  const float* W2    = (const float*)d_in[9];
  const float* b2    = (const float*)d_in[10];
  const float* ln1s  = (const float*)d_in[11];
  const float* ln1b  = (const float*)d_in[12];
  const float* ln2s  = (const float*)d_in[13];
  const float* ln2b  = (const float*)d_in[14];
  const float* Wout  = (const float*)d_in[15];
  const float* bout  = (const float*)d_in[16];

  // ---- workspace (104 MiB total — footprint validated rounds 3/6) ----
  char* ws = (char*)d_ws;
  __hip_bfloat16* WB   = (__hip_bfloat16*)ws;      // bf16 arena (~37.3 MiB)
  __hip_bfloat16* srcb = WB;                       //   524288
  __hip_bfloat16* wenc = WB + 524288;              //    65536
  __hip_bfloat16* wqkv = WB + 589824;              //  9437184
  __hip_bfloat16* wo   = WB + 10027008;            //  3145728
  __hip_bfloat16* w1   = WB + 13172736;            //  3145728
  __hip_bfloat16* w2   = WB + 16318464;            //  3145728
  __hip_bfloat16* wout = WB + 19464192;            //    65536
  __hip_bfloat16* xb  = (__hip_bfloat16*)(ws + (size_t)40 * 1048576);  // 16 MiB
  __hip_bfloat16* qkv = (__hip_bfloat16*)(ws + (size_t)56 * 1048576);  // 48 MiB
  __hip_bfloat16* ctxp = qkv;             // q slot — attn output
  __hip_bfloat16* ybuf = qkv + H_DIM;     // k slot — (x + attn_out) / (x + ff)
  __hip_bfloat16* hbuf = qkv + 2 * H_DIM; // v slot — relu hidden temp

  const dim3 blk(256);
  const dim3 blk512(512);

  // ---- ingest: all fp32 weights/src -> bf16 in ONE dispatch ----
  {
    CvtSeg s0{src,  srcb, 524288 / 4};
    CvtSeg s1{Wenc, wenc, 65536 / 4};
    CvtSeg s2{Wqkv, wqkv, 9437184 / 4};
    CvtSeg s3{Wo,   wo,   3145728 / 4};
    CvtSeg s4{W1,   w1,   3145728 / 4};
    CvtSeg s5{W2,   w2,   3145728 / 4};
    CvtSeg s6{Wout, wout, 65536 / 4};
    const int tot4 = (524288 + 65536 + 9437184 + 3 * 3145728 + 65536) / 4;
    cvt_all_k<<<dim3((tot4 + 255) / 256), blk, 0, stream>>>(s0, s1, s2, s3, s4, s5, s6);
  }

  // ---- encoder: x = src @ Wenc^T + benc   [8192,1024] (K=64 -> 1 tile) ----
  gemm_bt<0, 0, 0><<<dim3(H_DIM / 128, ROWS / 128), blk, 0, stream>>>(
      srcb, IN_DIM, wenc, benc, xb, H_DIM, nullptr, 0, ROWS, H_DIM, IN_DIM);

  for (int l = 0; l < NLAYER; l++) {
    // qkv = x @ Wqkv^T + bqkv   [8192,3072] — gemm_bt 24x64 grid,
    // 1536 blocks = 3 exact rounds @ 2 blk/CU
    gemm_bt<0, 0, 0><<<dim3(QKV_LD / 128, ROWS / 128), blk, 0, stream>>>(
        xb, H_DIM, wqkv + (size_t)l * QKV_LD * H_DIM, bqkv + l * QKV_LD,
        qkv, QKV_LD, nullptr, 0, ROWS, QKV_LD, H_DIM);
    // banded attention; ctx -> q slot
    attn_k<<<dim3(ROWS * NHEADS / 4), blk, 0, stream>>>(qkv);
    // ybuf = x + ctx @ Wo^T + bo   (residual fused) — 4x64=256 blocks
    gemm8_bt<0, 1><<<dim3(H_DIM / 256, ROWS / 128), blk512, 0, stream>>>(
        ctxp, QKV_LD, wo + (size_t)l * H_DIM * H_DIM, bo + l * H_DIM,
        ybuf, QKV_LD, xb, H_DIM, H_DIM);
    // x = LN(ybuf)
    ln_k<<<dim3(ROWS / 4), blk, 0, stream>>>(ybuf, QKV_LD, ln1s + l * H_DIM, ln1b + l * H_DIM, xb);
    // h = relu(x @ W1^T + b1) -> hbuf (v slot)
    gemm8_bt<1, 0><<<dim3(DFF_DIM / 256, ROWS / 128), blk512, 0, stream>>>(
        xb, H_DIM, w1 + (size_t)l * DFF_DIM * H_DIM, b1 + l * DFF_DIM,
        hbuf, QKV_LD, nullptr, 0, H_DIM);
    // ybuf = x + h @ W2^T + b2   (residual fused)
    gemm8_bt<0, 1><<<dim3(H_DIM / 256, ROWS / 128), blk512, 0, stream>>>(
        hbuf, QKV_LD, w2 + (size_t)l * H_DIM * DFF_DIM, b2 + l * H_DIM,
        ybuf, QKV_LD, xb, H_DIM, DFF_DIM);
    // x = LN(ybuf)
    ln_k<<<dim3(ROWS / 4), blk, 0, stream>>>(ybuf, QKV_LD, ln2s + l * H_DIM, ln2b + l * H_DIM, xb);
  }

  // ---- decoder: out = x @ Wout^T + bout   [8192,64] FP32 OUTPUT ----
  gemm_bt<0, 1, 0><<<dim3(1, ROWS / 128), blk, 0, stream>>>(
      xb, H_DIM, wout, bout, d_out, OUT_DIM, nullptr, 0, ROWS, OUT_DIM, H_DIM);
}

// Round 10
// 674.718 us; speedup vs baseline: 1.0345x; 1.0345x over previous
//
#include <hip/hip_runtime.h>
#include <hip/hip_bf16.h>

// Problem constants (from reference)
#define S_LEN   2048
#define BATCH   4
#define IN_DIM  64
#define H_DIM   1024
#define DFF_DIM 1024
#define OUT_DIM 64
#define NLAYER  3
#define NHEADS  4
#define DHEAD   256     // H / NHEAD
#define WIN     4       // banded window: j in [i-4, i]
#define ROWS    (S_LEN*BATCH)  // 8192 flattened (s,b) rows, row = s*B + b
#define QKV_LD  (3*H_DIM)      // 3072

// Established facts (rounds 0-20):
//  - r16/r18 = 682-696 us: QKV gemm_bt 16x16x32 (59.5 us, 858 TF, conflicts
//    0), Wo/W1/W2 gemm8 (~40-46 us each, ~400 TF), enc/dec gemm_bt.
//  - CLOSED: deep pipelines (r11/12/14/15 ~700 TF), XCD remaps (r17 FETCH
//    51->73 MB), 32x32x16 MFMA (r19: 6.29M bank conflicts/dispatch — the
//    chunk-XOR swizzle is conflict-free ONLY for the 16x16 fragment map;
//    QKV 59.5->70 us).
//  - Anomaly: Wo-family ~2.2x slower per round than QKV on THREE different
//    kernels. Clean separator: slow dispatches all write C STRIDED
//    (ldc=3072 into qkv k/v slots; LN then reads strided); fast ones write
//    dense. W1's A is dense xb yet W1 is slow -> A-stride exonerated.
//  - r20 (this): DENSE-SLOT RESTRUCTURE, zero extra memory. qkv 48 MB ->
//    three dense 16 MB buffers qb/kb/vb. QKV epilogue slot-scatters
//    (slot = col>>10, tile-uniform since 1024%128==0). attn reads dense
//    q/k/v, ctx->qb. Wo: A=qb C=kb (k dead). W1: C=vb (v dead). W2: A=vb
//    C=kb. All lda/ldc/ldr/ys = 1024. gemm_bt reverted to 16x16x32.
//    Predict: QKV unchanged; Wo-family -10-15 us each if stride was the
//    cause (total ~610-640), else null (~690) and ceiling declared next.

typedef __bf16 bf16x8 __attribute__((ext_vector_type(8)));
typedef float  f32x4  __attribute__((ext_vector_type(4)));

__device__ __forceinline__ float bfbits2f(unsigned int u) {
  union { unsigned int i; float f; } c; c.i = u << 16; return c.f;
}
__device__ __forceinline__ unsigned short f2bfbits(float f) {
  __hip_bfloat16 h = __float2bfloat16(f);
  return __builtin_bit_cast(unsigned short, h);
}

// async global->LDS, 16B per lane. LDS dest = wave-uniform base + lane*16.
__device__ __forceinline__ void g2l16(const void* g, void* l) {
  __builtin_amdgcn_global_load_lds((__attribute__((address_space(1))) void*)g,
                                   (__attribute__((address_space(3))) void*)l,
                                   16, 0, 0);
}

// ---------------------------------------------------------------------------
// Merged fp32->bf16 ingest: all 7 weight/src segments in ONE dispatch.
// ---------------------------------------------------------------------------
struct CvtSeg { const float* src; __hip_bfloat16* dst; int n4; };  // n4 = n/4

__global__ __launch_bounds__(256)
void cvt_all_k(CvtSeg s0, CvtSeg s1, CvtSeg s2, CvtSeg s3,
               CvtSeg s4, CvtSeg s5, CvtSeg s6)
{
  int i = blockIdx.x * 256 + threadIdx.x;   // index in unit of 4 elems
  CvtSeg seg;
  if      (i < s0.n4) { seg = s0; }
  else if ((i -= s0.n4) < s1.n4) { seg = s1; }
  else if ((i -= s1.n4) < s2.n4) { seg = s2; }
  else if ((i -= s2.n4) < s3.n4) { seg = s3; }
  else if ((i -= s3.n4) < s4.n4) { seg = s4; }
  else if ((i -= s4.n4) < s5.n4) { seg = s5; }
  else if ((i -= s5.n4) < s6.n4) { seg = s6; }
  else return;
  float4 v = *(const float4*)(seg.src + (size_t)i * 4);
  uint2 o;
  o.x = (unsigned)f2bfbits(v.x) | ((unsigned)f2bfbits(v.y) << 16);
  o.y = (unsigned)f2bfbits(v.z) | ((unsigned)f2bfbits(v.w) << 16);
  *(uint2*)(seg.dst + (size_t)i * 4) = o;
}

// ---------------------------------------------------------------------------
// gemm_bt: 128x128 tile, BK=64, 256 thr, 2 blk/CU — encoder, QKV, decoder.
// 16x16x32 MFMA (measured-best). SLOTC=1: C scatter into 3 dense 16MB slot
// buffers: addr = Cb + (col>>10)*8M + row*1024 + (col&1023).
// ---------------------------------------------------------------------------
template<int RELU, int OUTF32, int ADDRES, int SLOTC>
__global__ __launch_bounds__(256, 2)
void gemm_bt(const __hip_bfloat16* __restrict__ A, int lda,
             const __hip_bfloat16* __restrict__ B,
             const float* __restrict__ bias,
             void* __restrict__ Cp, int ldc,
             const __hip_bfloat16* __restrict__ R, int ldr,
             int M, int N, int K)
{
  __shared__ __align__(16) __hip_bfloat16 As[128 * 64];
  __shared__ __align__(16) __hip_bfloat16 Bs[128 * 64];

  const int tid  = threadIdx.x;
  const int lane = tid & 63;
  const int wave = tid >> 6;
  const int quad = lane >> 4;
  const int l16  = lane & 15;

  const int gx  = gridDim.x;
  const int lin = blockIdx.y * gx + blockIdx.x;
  const int gsz = 4 * gx;
  const int mt  = (lin / gsz) * 4 + (lin & 3);
  const int nt  = (lin % gsz) >> 2;
  const int m0 = mt * 128;
  const int n0 = nt * 128;

  const int wr = (wave >> 1) * 64;   // wave's 64x64 sub-tile
  const int wc = (wave & 1) * 64;

  int arow[4], acol[4], brow[4];
#pragma unroll
  for (int s = 0; s < 4; s++) {
    const int p = tid + (s << 8);
    arow[s] = p >> 3;
    acol[s] = ((p & 7) ^ ((p >> 3) & 7)) * 8;
    brow[s] = min(n0 + arow[s], N - 1);   // clamp for N edge
  }

  f32x4 acc[4][4] = {};
  const int nk = K >> 6;

  for (int t = 0; t < nk; ++t) {
    const int k0 = t << 6;
#pragma unroll
    for (int s = 0; s < 4; s++) {
      const int lo = (wave * 64 + (s << 8)) * 8;   // chunk*8 elems
      g2l16(A + (size_t)(m0 + arow[s]) * lda + k0 + acol[s], &As[lo]);
      g2l16(B + (size_t)brow[s] * K + k0 + acol[s], &Bs[lo]);
    }
    __syncthreads();

#pragma unroll
    for (int kh = 0; kh < 2; kh++) {
      bf16x8 af[4], bfr[4];
#pragma unroll
      for (int i = 0; i < 4; i++) {
        const int row = wr + i * 16 + l16;
        const int c   = (kh * 4 + quad) ^ (row & 7);
        af[i] = *(const bf16x8*)&As[row * 64 + c * 8];
      }
#pragma unroll
      for (int j = 0; j < 4; j++) {
        const int row = wc + j * 16 + l16;
        const int c   = (kh * 4 + quad) ^ (row & 7);
        bfr[j] = *(const bf16x8*)&Bs[row * 64 + c * 8];
      }
#pragma unroll
      for (int i = 0; i < 4; i++)
#pragma unroll
        for (int j = 0; j < 4; j++)
          acc[i][j] = __builtin_amdgcn_mfma_f32_16x16x32_bf16(af[i], bfr[j], acc[i][j], 0, 0, 0);
    }
    __syncthreads();
  }

#pragma unroll
  for (int j = 0; j < 4; j++) {
    int col = n0 + wc + j * 16 + l16;
    if (col < N) {
      float bv = bias[col];
#pragma unroll
      for (int i = 0; i < 4; i++) {
        int row = m0 + wr + i * 16 + quad * 4;
#pragma unroll
        for (int r = 0; r < 4; r++) {
          float v = acc[i][j][r] + bv;
          if (RELU) v = fmaxf(v, 0.f);
          if (ADDRES) v += __bfloat162float(R[(size_t)(row + r) * ldr + col]);
          if (SLOTC) {
            __hip_bfloat16* cp = (__hip_bfloat16*)Cp
                + ((size_t)(col >> 10) << 23)            // slot * 8192*1024
                + (size_t)(row + r) * 1024 + (col & 1023);
            *cp = __float2bfloat16(v);
          } else if (OUTF32) {
            ((float*)Cp)[(size_t)(row + r) * ldc + col] = v;
          } else {
            ((__hip_bfloat16*)Cp)[(size_t)(row + r) * ldc + col] = __float2bfloat16(v);
          }
        }
      }
    }
  }
}

// ---------------------------------------------------------------------------
// gemm8_bt: 128(M)x256(N), BK=64, 512 thr (8 waves 2Mx4N, wave owns 64x64),
// 8-phase window over 2 K-tiles, 1 half-slot stage/phase, vmcnt(4) at ph4/8.
// Measured-best for Wo/W1/W2 (N=1024 -> 256 blocks, exact 1-round packing).
// UNCHANGED structurally; callers now pass dense (1024-stride) buffers.
// ---------------------------------------------------------------------------
#define ST_A(BUF, H, KO)                                                      \
  g2l16(Ab + (size_t)((H) * 64 + sarow) * lda + (KO) + sacol,                 \
        &lds[BUF][(H) << 12] + (tid << 3))
#define ST_B(BUF, H, KO)                                                      \
  do {                                                                        \
    g2l16(Bb + (size_t)((H) * 128 + sbrow) * K + (KO) + sbcol,                \
          &lds[BUF][8192 + ((H) << 13)] + (tid << 3));                        \
    g2l16(Bb + (size_t)((H) * 128 + sbrow + 64) * K + (KO) + sbcol,           \
          &lds[BUF][8192 + ((H) << 13)] + ((tid + 512) << 3));                \
  } while (0)

#define RD_AF(ASL, FRB)                                                       \
  do {                                                                        \
    _Pragma("unroll") for (int j_ = 0; j_ < 2; j_++) {                        \
      const int r_ = ((FRB) + j_) * 16 + l16;                                 \
      const int x_ = r_ & 7;                                                  \
      af[j_][0] = *(const bf16x8*)&(ASL)[r_ * 64 + ((quad ^ x_) << 3)];       \
      af[j_][1] = *(const bf16x8*)&(ASL)[r_ * 64 + (((4 + quad) ^ x_) << 3)]; \
    }                                                                         \
  } while (0)
#define RD_BQ(BSL, FCB)                                                       \
  do {                                                                        \
    _Pragma("unroll") for (int j_ = 0; j_ < 2; j_++) {                        \
      const int r_ = brow_base + ((FCB) + j_) * 16 + l16;                     \
      const int x_ = r_ & 7;                                                  \
      bq[(FCB) + j_][0] = *(const bf16x8*)&(BSL)[r_ * 64 + ((quad ^ x_) << 3)]; \
      bq[(FCB) + j_][1] = *(const bf16x8*)&(BSL)[r_ * 64 + (((4 + quad) ^ x_) << 3)]; \
    }                                                                         \
  } while (0)
#define MM(FRB, FCB)                                                          \
  do {                                                                        \
    _Pragma("unroll") for (int ks_ = 0; ks_ < 2; ks_++)                       \
      _Pragma("unroll") for (int i_ = 0; i_ < 2; i_++)                        \
        _Pragma("unroll") for (int j_ = 0; j_ < 2; j_++)                      \
          acc[(FRB) + i_][(FCB) + j_] =                                       \
              __builtin_amdgcn_mfma_f32_16x16x32_bf16(                        \
                  af[i_][ks_], bq[(FCB) + j_][ks_],                           \
                  acc[(FRB) + i_][(FCB) + j_], 0, 0, 0);                      \
  } while (0)

#define PH8(READS, STAGE, WAIT, MFMA)                                         \
  do {                                                                        \
    READS; STAGE; WAIT;                                                       \
    __builtin_amdgcn_s_barrier();                                             \
    asm volatile("s_waitcnt lgkmcnt(0)" ::: "memory");                        \
    __builtin_amdgcn_sched_barrier(0);                                        \
    __builtin_amdgcn_s_setprio(1);                                            \
    MFMA;                                                                     \
    __builtin_amdgcn_s_setprio(0);                                            \
    __builtin_amdgcn_s_barrier();                                             \
  } while (0)

#define W4CNT                                                                 \
  do {                                                                        \
    if (pf) { asm volatile("s_waitcnt vmcnt(4)" ::: "memory"); }              \
    else    { asm volatile("s_waitcnt vmcnt(0)" ::: "memory"); }              \
  } while (0)

template<int RELU, int ADDRES>
__global__ __launch_bounds__(512, 1)
void gemm8_bt(const __hip_bfloat16* __restrict__ A, int lda,
              const __hip_bfloat16* __restrict__ B,
              const float* __restrict__ bias,
              __hip_bfloat16* __restrict__ C, int ldc,
              const __hip_bfloat16* __restrict__ Rr, int ldr,
              int K)
{
  __shared__ __align__(16) __hip_bfloat16 lds[2][24576];  // 96 KiB

  const int tid  = threadIdx.x;
  const int lane = tid & 63;
  const int wave = tid >> 6;
  const int quad = lane >> 4;
  const int l16  = lane & 15;
  const int wm   = wave >> 2;        // 0..1 (M half)
  const int wn   = wave & 3;         // 0..3 (N quarter)
  const int bh   = wn >> 1;          // wave's B-half
  const int brow_base = (wn & 1) * 64;

  const int gx  = gridDim.x;
  const int lin = blockIdx.y * gx + blockIdx.x;
  const int gsz = 4 * gx;
  const int mt  = (lin / gsz) * 4 + (lin & 3);
  const int nt  = (lin % gsz) >> 2;
  const int m0 = mt * 128;
  const int n0 = nt * 256;

  const __hip_bfloat16* Ab = A + (size_t)m0 * lda;
  const __hip_bfloat16* Bb = B + (size_t)n0 * K;

  const int sarow = tid >> 3;                         // A: rows 0..63
  const int sacol = ((tid & 7) ^ (sarow & 7)) << 3;
  const int sbrow = sarow;
  const int sbcol = sacol;

  const __hip_bfloat16* As0 = &lds[0][wm << 12];
  const __hip_bfloat16* As1 = &lds[1][wm << 12];
  const __hip_bfloat16* Bs0 = &lds[0][8192 + (bh << 13)];
  const __hip_bfloat16* Bs1 = &lds[1][8192 + (bh << 13)];

  f32x4 acc[4][4] = {};
  bf16x8 af[2][2], bq[4][2];

  const int NI = K >> 7;   // iterations of 2 K-tiles

  ST_A(0, 0, 0); ST_A(0, 1, 0);
  ST_B(0, 0, 0); ST_B(0, 1, 0);
  ST_B(1, 0, 64); ST_B(1, 1, 64);
  asm volatile("s_waitcnt vmcnt(4)" ::: "memory");   // buf0 landed
  __builtin_amdgcn_s_barrier();

  for (int i = 0; i < NI; ++i) {
    const int k1 = (i << 7) + 64;    // K-tile 2i+1
    const int k2 = k1 + 64;          // K-tile 2i+2
    const int k3 = k1 + 128;         // K-tile 2i+3
    const bool pf = (i + 1) < NI;

    PH8(RD_AF(As0, 0); RD_BQ(Bs0, 0),  ST_A(1, 0, k1),              , MM(0, 0));
    PH8(RD_BQ(Bs0, 2),                 ST_A(1, 1, k1),              , MM(0, 2));
    PH8(RD_AF(As0, 2),                 if (pf) ST_B(0, 0, k2),      , MM(2, 0));
    PH8(                             , if (pf) ST_B(0, 1, k2), W4CNT, MM(2, 2));
    PH8(RD_AF(As1, 0); RD_BQ(Bs1, 0),  if (pf) ST_A(0, 0, k2),      , MM(0, 0));
    PH8(RD_BQ(Bs1, 2),                 if (pf) ST_A(0, 1, k2),      , MM(0, 2));
    PH8(RD_AF(As1, 2),                 if (pf) ST_B(1, 0, k3),      , MM(2, 0));
    PH8(                             , if (pf) ST_B(1, 1, k3), W4CNT, MM(2, 2));
  }

#pragma unroll
  for (int jn = 0; jn < 4; jn++) {
    const int col = n0 + wn * 64 + jn * 16 + l16;
    const float bv = bias[col];
#pragma unroll
    for (int im = 0; im < 4; im++) {
      const int row0 = m0 + wm * 64 + im * 16 + quad * 4;
      const f32x4 a = acc[im][jn];
#pragma unroll
      for (int rr = 0; rr < 4; rr++) {
        float v = a[rr] + bv;
        if (RELU) v = fmaxf(v, 0.f);
        if (ADDRES) v += __bfloat162float(Rr[(size_t)(row0 + rr) * ldr + col]);
        C[(size_t)(row0 + rr) * ldc + col] = __float2bfloat16(v);
      }
    }
  }
}

// ---------------------------------------------------------------------------
// Banded attention (one wave per (s,b,h)) — dense q/k/v buffers, stride 1024.
// ctx overwrites qb.
// ---------------------------------------------------------------------------
__global__ __launch_bounds__(256)
void attn_k(__hip_bfloat16* __restrict__ qb,
            const __hip_bfloat16* __restrict__ kb,
            const __hip_bfloat16* __restrict__ vb)
{
  const int gw   = (blockIdx.x << 2) + (threadIdx.x >> 6);
  const int lane = threadIdx.x & 63;
  const int h = gw & (NHEADS - 1);
  const int b = (gw >> 2) & (BATCH - 1);
  const int s = gw >> 4;
  const size_t hoff = (size_t)h * DHEAD + (lane << 2);

  float q0, q1, q2, q3;
  {
    uint2 t = *(const uint2*)(qb + (size_t)(s * BATCH + b) * H_DIM + hoff);
    q0 = bfbits2f(t.x & 0xffff); q1 = bfbits2f(t.x >> 16);
    q2 = bfbits2f(t.y & 0xffff); q3 = bfbits2f(t.y >> 16);
  }

  float sc[WIN + 1];
#pragma unroll
  for (int jj = 0; jj <= WIN; jj++) {
    int j = s - WIN + jj;           // wave-uniform
    float v = -1e30f;
    if (j >= 0) {
      uint2 t = *(const uint2*)(kb + (size_t)(j * BATCH + b) * H_DIM + hoff);
      float p = q0 * bfbits2f(t.x & 0xffff) + q1 * bfbits2f(t.x >> 16)
              + q2 * bfbits2f(t.y & 0xffff) + q3 * bfbits2f(t.y >> 16);
#pragma unroll
      for (int o = 32; o; o >>= 1) p += __shfl_xor(p, o);
      v = p * 0.0625f;              // 1/sqrt(256)
    }
    sc[jj] = v;
  }

  float mx = sc[0];
#pragma unroll
  for (int jj = 1; jj <= WIN; jj++) mx = fmaxf(mx, sc[jj]);
  float p[WIN + 1], den = 0.f;
#pragma unroll
  for (int jj = 0; jj <= WIN; jj++) { p[jj] = __expf(sc[jj] - mx); den += p[jj]; }

  float a0 = 0.f, a1 = 0.f, a2 = 0.f, a3 = 0.f;
#pragma unroll
  for (int jj = 0; jj <= WIN; jj++) {
    int j = s - WIN + jj;
    if (j >= 0) {
      uint2 t = *(const uint2*)(vb + (size_t)(j * BATCH + b) * H_DIM + hoff);
      a0 += p[jj] * bfbits2f(t.x & 0xffff); a1 += p[jj] * bfbits2f(t.x >> 16);
      a2 += p[jj] * bfbits2f(t.y & 0xffff); a3 += p[jj] * bfbits2f(t.y >> 16);
    }
  }
  float rl = 1.f / den;
  uint2 o;
  o.x = (unsigned)f2bfbits(a0 * rl) | ((unsigned)f2bfbits(a1 * rl) << 16);
  o.y = (unsigned)f2bfbits(a2 * rl) | ((unsigned)f2bfbits(a3 * rl) << 16);
  *(uint2*)(qb + (size_t)(s * BATCH + b) * H_DIM + hoff) = o;  // ctx -> qb
}

// ---------------------------------------------------------------------------
// LayerNorm, one wave per row (shuffle-only).
// ---------------------------------------------------------------------------
__global__ __launch_bounds__(256)
void ln_k(const __hip_bfloat16* __restrict__ y, int ys,
          const float* __restrict__ g, const float* __restrict__ be,
          __hip_bfloat16* __restrict__ xout)
{
  const int row  = blockIdx.x * 4 + (threadIdx.x >> 6);
  const int lane = threadIdx.x & 63;
  const int e0   = lane * 16;
  const __hip_bfloat16* yp = y + (size_t)row * ys + e0;

  uint2 v[4];
  *(uint4*)&v[0] = *(const uint4*)yp;
  *(uint4*)&v[2] = *(const uint4*)(yp + 8);
  float t[16];
#pragma unroll
  for (int k = 0; k < 4; k++) {
    t[k * 4 + 0] = bfbits2f(v[k].x & 0xffff);
    t[k * 4 + 1] = bfbits2f(v[k].x >> 16);
    t[k * 4 + 2] = bfbits2f(v[k].y & 0xffff);
    t[k * 4 + 3] = bfbits2f(v[k].y >> 16);
  }
  float s = 0.f, ss = 0.f;
#pragma unroll
  for (int k = 0; k < 16; k++) { s += t[k]; ss += t[k] * t[k]; }
#pragma unroll
  for (int o = 32; o; o >>= 1) { s += __shfl_xor(s, o); ss += __shfl_xor(ss, o); }

  const float inv  = 1.f / (float)H_DIM;
  const float mean = s * inv;
  const float var  = ss * inv - mean * mean;   // biased var (jnp.var default)
  const float rstd = rsqrtf(var + 1e-5f);

  float4 gv[4], bv[4];
#pragma unroll
  for (int k = 0; k < 4; k++) {
    gv[k] = *(const float4*)(g + e0 + k * 4);
    bv[k] = *(const float4*)(be + e0 + k * 4);
  }
  uint2 ob[4];
#pragma unroll
  for (int k = 0; k < 4; k++) {
    float o0 = (t[k*4+0] - mean) * rstd * gv[k].x + bv[k].x;
    float o1 = (t[k*4+1] - mean) * rstd * gv[k].y + bv[k].y;
    float o2 = (t[k*4+2] - mean) * rstd * gv[k].z + bv[k].z;
    float o3 = (t[k*4+3] - mean) * rstd * gv[k].w + bv[k].w;
    ob[k].x = (unsigned)f2bfbits(o0) | ((unsigned)f2bfbits(o1) << 16);
    ob[k].y = (unsigned)f2bfbits(o2) | ((unsigned)f2bfbits(o3) << 16);
  }
  __hip_bfloat16* xp = xout + (size_t)row * H_DIM + e0;
  *(uint4*)xp       = *(const uint4*)&ob[0];
  *(uint4*)(xp + 8) = *(const uint4*)&ob[2];
}

// ---------------------------------------------------------------------------
extern "C" void kernel_launch(void* const* d_in, const int* in_sizes, int n_in,
                              void* d_out, int out_size, void* d_ws, size_t ws_size,
                              hipStream_t stream) {
  const float* src   = (const float*)d_in[0];
  const float* Wenc  = (const float*)d_in[1];
  const float* benc  = (const float*)d_in[2];
  const float* Wqkv  = (const float*)d_in[3];
  const float* bqkv  = (const float*)d_in[4];
  const float* Wo    = (const float*)d_in[5];
  const float* bo    = (const float*)d_in[6];
  const float* W1    = (const float*)d_in[7];
  const float* b1    = (const float*)d_in[8];
  const float* W2    = (const float*)d_in[9];
  const float* b2    = (const float*)d_in[10];
  const float* ln1s  = (const float*)d_in[11];
  const float* ln1b  = (const float*)d_in[12];
  const float* ln2s  = (const float*)d_in[13];
  const float* ln2b  = (const float*)d_in[14];
  const float* Wout  = (const float*)d_in[15];
  const float* bout  = (const float*)d_in[16];

  // ---- workspace (104 MiB total — footprint unchanged from r16/r18) ----
  char* ws = (char*)d_ws;
  __hip_bfloat16* WB   = (__hip_bfloat16*)ws;      // bf16 arena (~37.3 MiB)
  __hip_bfloat16* srcb = WB;                       //   524288
  __hip_bfloat16* wenc = WB + 524288;              //    65536
  __hip_bfloat16* wqkv = WB + 589824;              //  9437184
  __hip_bfloat16* wo   = WB + 10027008;            //  3145728
  __hip_bfloat16* w1   = WB + 13172736;            //  3145728
  __hip_bfloat16* w2   = WB + 16318464;            //  3145728
  __hip_bfloat16* wout = WB + 19464192;            //    65536
  __hip_bfloat16* xb  = (__hip_bfloat16*)(ws + (size_t)40 * 1048576);  // 16 MiB
  // qkv region 48 MiB, now THREE DENSE 16 MiB buffers:
  __hip_bfloat16* qb  = (__hip_bfloat16*)(ws + (size_t)56 * 1048576);  // q / ctx
  __hip_bfloat16* kb  = qb + (size_t)ROWS * H_DIM;                     // k / ybuf
  __hip_bfloat16* vb  = kb + (size_t)ROWS * H_DIM;                     // v / hbuf

  const dim3 blk(256);
  const dim3 blk512(512);

  // ---- ingest: all fp32 weights/src -> bf16 in ONE dispatch ----
  {
    CvtSeg s0{src,  srcb, 524288 / 4};
    CvtSeg s1{Wenc, wenc, 65536 / 4};
    CvtSeg s2{Wqkv, wqkv, 9437184 / 4};
    CvtSeg s3{Wo,   wo,   3145728 / 4};
    CvtSeg s4{W1,   w1,   3145728 / 4};
    CvtSeg s5{W2,   w2,   3145728 / 4};
    CvtSeg s6{Wout, wout, 65536 / 4};
    const int tot4 = (524288 + 65536 + 9437184 + 3 * 3145728 + 65536) / 4;
    cvt_all_k<<<dim3((tot4 + 255) / 256), blk, 0, stream>>>(s0, s1, s2, s3, s4, s5, s6);
  }

  // ---- encoder: x = src @ Wenc^T + benc   [8192,1024] (K=64 -> 1 tile) ----
  gemm_bt<0, 0, 0, 0><<<dim3(H_DIM / 128, ROWS / 128), blk, 0, stream>>>(
      srcb, IN_DIM, wenc, benc, xb, H_DIM, nullptr, 0, ROWS, H_DIM, IN_DIM);

  for (int l = 0; l < NLAYER; l++) {
    // qkv = x @ Wqkv^T + bqkv — slot-scatter into dense qb/kb/vb
    gemm_bt<0, 0, 0, 1><<<dim3(QKV_LD / 128, ROWS / 128), blk, 0, stream>>>(
        xb, H_DIM, wqkv + (size_t)l * QKV_LD * H_DIM, bqkv + l * QKV_LD,
        qb, 0, nullptr, 0, ROWS, QKV_LD, H_DIM);
    // banded attention on dense q/k/v; ctx -> qb
    attn_k<<<dim3(ROWS * NHEADS / 4), blk, 0, stream>>>(qb, kb, vb);
    // ybuf(kb) = x + ctx @ Wo^T + bo  (k dead after attn) — all dense
    gemm8_bt<0, 1><<<dim3(H_DIM / 256, ROWS / 128), blk512, 0, stream>>>(
        qb, H_DIM, wo + (size_t)l * H_DIM * H_DIM, bo + l * H_DIM,
        kb, H_DIM, xb, H_DIM, H_DIM);
    // x = LN(kb)
    ln_k<<<dim3(ROWS / 4), blk, 0, stream>>>(kb, H_DIM, ln1s + l * H_DIM, ln1b + l * H_DIM, xb);
    // h(vb) = relu(x @ W1^T + b1)  (v dead after attn)
    gemm8_bt<1, 0><<<dim3(DFF_DIM / 256, ROWS / 128), blk512, 0, stream>>>(
        xb, H_DIM, w1 + (size_t)l * DFF_DIM * H_DIM, b1 + l * DFF_DIM,
        vb, H_DIM, nullptr, 0, H_DIM);
    // ybuf(kb) = x + h @ W2^T + b2
    gemm8_bt<0, 1><<<dim3(H_DIM / 256, ROWS / 128), blk512, 0, stream>>>(
        vb, H_DIM, w2 + (size_t)l * H_DIM * DFF_DIM, b2 + l * H_DIM,
        kb, H_DIM, xb, H_DIM, DFF_DIM);
    // x = LN(kb)
    ln_k<<<dim3(ROWS / 4), blk, 0, stream>>>(kb, H_DIM, ln2s + l * H_DIM, ln2b + l * H_DIM, xb);
  }

  // ---- decoder: out = x @ Wout^T + bout   [8192,64] FP32 OUTPUT ----
  gemm_bt<0, 1, 0, 0><<<dim3(1, ROWS / 128), blk, 0, stream>>>(
      xb, H_DIM, wout, bout, d_out, OUT_DIM, nullptr, 0, ROWS, OUT_DIM, H_DIM);
}